// Round 9
// baseline (518.120 us; speedup 1.0000x reference)
//
#include <hip/hip_runtime.h>
#include <hip/hip_fp16.h>
#include <cstdint>
#include <cstddef>

#define S_LEN 2048
#define BATCH 2
#define EMB   1024
#define NHEAD 16
#define HDIM  64

typedef short short8 __attribute__((ext_vector_type(8)));   // 8 bf16 (4 VGPRs)
typedef float f32x4  __attribute__((ext_vector_type(4)));

__device__ __forceinline__ unsigned short f2b(float f) {
    unsigned int u = __float_as_uint(f);
    u = (u + 0x7FFFu + ((u >> 16) & 1u)) >> 16;   // RNE
    return (unsigned short)u;
}
__device__ __forceinline__ unsigned int pk2(float a, float b) {
    return (unsigned int)f2b(a) | ((unsigned int)f2b(b) << 16);
}
__device__ __forceinline__ float b2f_lo(unsigned int u) { return __uint_as_float(u << 16); }
__device__ __forceinline__ float b2f_hi(unsigned int u) { return __uint_as_float(u & 0xFFFF0000u); }

// async global->LDS, 16B per lane. LDS dest is wave-uniform base + lane*16.
__device__ __forceinline__ void gload_lds16(const ushort* g, ushort* l) {
    __builtin_amdgcn_global_load_lds(
        (const __attribute__((address_space(1))) void*)g,
        (__attribute__((address_space(3))) void*)l, 16, 0, 0);
}

// ---------------------------------------------------------------------------
// Precast fp32 -> bf16 (RNE, identical to the f2b the GEMM used in-kernel).
// ---------------------------------------------------------------------------
__global__ __launch_bounds__(256)
void cast3(const float* __restrict__ s0, const float* __restrict__ s1,
           const float* __restrict__ s2, ushort* __restrict__ d0,
           ushort* __restrict__ d1, ushort* __restrict__ d2)
{
    const float* s = (blockIdx.y == 0) ? s0 : (blockIdx.y == 1) ? s1 : s2;
    ushort*      d = (blockIdx.y == 0) ? d0 : (blockIdx.y == 1) ? d1 : d2;
    const size_t i = ((size_t)blockIdx.x * 256 + threadIdx.x) * 8;
    const float4 a = *(const float4*)(s + i);
    const float4 b = *(const float4*)(s + i + 4);
    *(uint4*)(d + i) = make_uint4(pk2(a.x, a.y), pk2(a.z, a.w),
                                  pk2(b.x, b.y), pk2(b.z, b.w));
}

__global__ __launch_bounds__(256)
void cast4(const float* __restrict__ s0, const float* __restrict__ s1,
           const float* __restrict__ s2, const float* __restrict__ s3,
           ushort* __restrict__ d0, ushort* __restrict__ d1,
           ushort* __restrict__ d2, ushort* __restrict__ d3)
{
    const float* s = (blockIdx.y == 0) ? s0 : (blockIdx.y == 1) ? s1
                   : (blockIdx.y == 2) ? s2 : s3;
    ushort*      d = (blockIdx.y == 0) ? d0 : (blockIdx.y == 1) ? d1
                   : (blockIdx.y == 2) ? d2 : d3;
    const size_t i = ((size_t)blockIdx.x * 256 + threadIdx.x) * 8;
    const float4 a = *(const float4*)(s + i);
    const float4 b = *(const float4*)(s + i + 4);
    *(uint4*)(d + i) = make_uint4(pk2(a.x, a.y), pk2(a.z, a.w),
                                  pk2(b.x, b.y), pk2(b.z, b.w));
}

// ---------------------------------------------------------------------------
// bf16 GEMM: C[M=4096,N=1024] = A[M,K=1024] @ W[N,K]^T + bias.
// 128x128 tile, BK=32, 512 thr / 8 waves, global_load_lds width-16 staging,
// double-buffered LDS, XOR seg-swizzle (src-side + read-side). Unchanged R2.
// ---------------------------------------------------------------------------
__device__ __forceinline__ void gemm_core(
    ushort (*As)[128 * 32], ushort (*Bs)[128 * 32],
    const ushort* __restrict__ A, const ushort* __restrict__ W,
    const float* __restrict__ bias, void* __restrict__ out_,
    float scale, int mode)
{
    constexpr int K  = EMB;
    constexpr int NT = K / 32;           // 32 K-steps

    const int t    = threadIdx.x;
    const int lane = t & 63;
    const int wave = t >> 6;
    const int quad = lane >> 4;
    const int l15  = lane & 15;
    const int wm   = wave >> 2;          // 0..1
    const int wn   = wave & 3;           // 0..3
    const int m0   = blockIdx.x * 128;
    const int n0   = blockIdx.y * 128;

    const int srow = t >> 2;
    const int sseg = ((t & 3) ^ ((srow >> 1) & 3)) << 3;   // elems
    const ushort* gA = A + (size_t)(m0 + srow) * K + sseg;
    const ushort* gW = W + (size_t)(n0 + srow) * K + sseg;

    f32x4 acc[4][2];
#pragma unroll
    for (int mi = 0; mi < 4; ++mi)
#pragma unroll
        for (int ni = 0; ni < 2; ++ni) acc[mi][ni] = (f32x4){0.f, 0.f, 0.f, 0.f};

#define STAGE(buf, kt) do {                         \
        gload_lds16(gA + (kt) * 32, &As[buf][t * 8]); \
        gload_lds16(gW + (kt) * 32, &Bs[buf][t * 8]); \
    } while (0)

    STAGE(0, 0);
    __syncthreads();

    for (int kt = 0; kt < NT; ++kt) {
        const int cur = kt & 1;
        if (kt + 1 < NT) STAGE(cur ^ 1, kt + 1);
        short8 af[4], bf[2];
#pragma unroll
        for (int mi = 0; mi < 4; ++mi) {
            const int ra = wm * 64 + mi * 16 + l15;
            af[mi] = *(const short8*)&As[cur][ra * 32 + ((quad ^ ((ra >> 1) & 3)) << 3)];
        }
#pragma unroll
        for (int ni = 0; ni < 2; ++ni) {
            const int rb = wn * 32 + ni * 16 + l15;
            bf[ni] = *(const short8*)&Bs[cur][rb * 32 + ((quad ^ ((rb >> 1) & 3)) << 3)];
        }
#pragma unroll
        for (int mi = 0; mi < 4; ++mi)
#pragma unroll
            for (int ni = 0; ni < 2; ++ni)
                acc[mi][ni] = __builtin_amdgcn_mfma_f32_16x16x32_bf16(
                    af[mi], bf[ni], acc[mi][ni], 0, 0, 0);
        __syncthreads();
    }
#undef STAGE

#pragma unroll
    for (int mi = 0; mi < 4; ++mi)
#pragma unroll
        for (int ni = 0; ni < 2; ++ni) {
            const int col = n0 + wn * 32 + ni * 16 + l15;
            const float bc = bias[col];
#pragma unroll
            for (int r = 0; r < 4; ++r) {
                const int rg = m0 + wm * 64 + mi * 16 + quad * 4 + r;
                const float v = (acc[mi][ni][r] + bc) * scale;
                if (mode == 0) {
                    ((float*)out_)[(size_t)rg * EMB + col] = v;
                } else {
                    const int s  = rg >> 1;
                    const int bb = rg & 1;
                    const int h  = col >> 6;
                    const int d  = col & 63;
                    if (mode == 1)
                        ((ushort*)out_)[(((size_t)(bb * NHEAD + h)) * S_LEN + s) * HDIM + d] = f2b(v);
                    else
                        ((ushort*)out_)[(((size_t)(bb * NHEAD + h)) * HDIM + d) * S_LEN + s] = f2b(v);
                }
            }
        }
}

__global__ __launch_bounds__(512, 2)
void gemm_qkv(const ushort* __restrict__ qi, const ushort* __restrict__ ki,
              const ushort* __restrict__ vi,
              const ushort* __restrict__ qW, const ushort* __restrict__ kW,
              const ushort* __restrict__ vW,
              const float* __restrict__ qB, const float* __restrict__ kB,
              const float* __restrict__ vB,
              ushort* __restrict__ qO, ushort* __restrict__ kO,
              ushort* __restrict__ vO)
{
    __shared__ ushort As[2][128 * 32];
    __shared__ ushort Bs[2][128 * 32];
    const int z = blockIdx.z;
    const ushort* A    = (z == 0) ? qi : (z == 1) ? ki : vi;
    const ushort* W    = (z == 0) ? qW : (z == 1) ? kW : vW;
    const float* bias  = (z == 0) ? qB : (z == 1) ? kB : vB;
    ushort* out        = (z == 0) ? qO : (z == 1) ? kO : vO;
    const float scale  = (z == 0) ? 0.125f : 1.0f;
    const int   mode   = (z == 2) ? 2 : 1;
    gemm_core(As, Bs, A, W, bias, out, scale, mode);
}

__global__ __launch_bounds__(512, 2)
void gemm_z(const ushort* __restrict__ A, const ushort* __restrict__ W,
            const float* __restrict__ bias, float* __restrict__ out)
{
    __shared__ ushort As[2][128 * 32];
    __shared__ ushort Bs[2][128 * 32];
    gemm_core(As, Bs, A, W, bias, out, 1.0f, 0);
}

// ---------------------------------------------------------------------------
// Fused attention — R8 "pavg-ectomy" (resubmit; R8 bench was an infra
// failure, not a kernel verdict): pavg moved OUT of this kernel entirely
// (recomputed later from q/k + stored rinv). Seven-round law: waves/SIMD ~=
// 256/VGPR_Count, and a 512-thr block needs 4 waves/SIMD on every SIMD ->
// the body must be <= 64 VGPR for 2-block residency. Removing pavg (-32 regs,
// -~100 VALU/head, -33MB partial writes) brings natural pressure to ~68;
// __launch_bounds__(512,4) forces the 64 budget (R6 proved it binds). Worst
// case a few regs spill (~tens of MB, not R6's 0.8 GB of pavg state).
// Everything else identical to the proven 278-us R7 structure.
// ---------------------------------------------------------------------------
#define PLD 2056   // 2048 + 8 pad (ushorts)
__global__ __launch_bounds__(512, 4)
void attn_bf16(const ushort* __restrict__ qw, const ushort* __restrict__ kw,
               const ushort* __restrict__ vt, ushort* __restrict__ ao,
               float* __restrict__ rinv_ws)
{
    __shared__ ushort pLds[16 * PLD];      // 65792 B (unnormalized e, bf16)
    __shared__ float  redS[8 * 16];        // per-wave row-sum partials
    __shared__ float  red2[4 * 16 * 16];   // PV khalf partials

    const int t     = threadIdx.x;
    const int lane  = t & 63;
    const int wave  = t >> 6;              // 0..7
    const int quad  = lane >> 4;
    const int l15   = lane & 15;
    const int rbase = quad * 4;

    const int bid     = blockIdx.x;
    const int logical = (bid & 7) * 64 + (bid >> 3);
    const int qt      = logical & 127;     // q-tile 0..127
    const int rest    = logical >> 7;      // 0..3
    const int b       = rest & 1;
    const int g       = rest >> 1;         // head group
    const int sq0     = qt * 16;

    const int ntile = wave & 3;            // PV d-tile
    const int khalf = wave >> 2;           // PV k-half

    for (int hh = 0; hh < 8; ++hh) {
        const int h  = g * 8 + hh;
        const int bh = b * NHEAD + h;
        const ushort* qbase = qw + ((size_t)bh * S_LEN + sq0) * HDIM;
        const ushort* kbse  = kw + (size_t)bh * S_LEN * HDIM;

        const short8 qf0 = *(const short8*)(qbase + l15 * HDIM + quad * 8);
        const short8 qf1 = *(const short8*)(qbase + l15 * HDIM + 32 + quad * 8);

        // ---- scores + exp + stage (wave owns cols [wave*256, wave*256+256)) ----
        float s4[4] = {0.f, 0.f, 0.f, 0.f};
#pragma unroll
        for (int ti = 0; ti < 16; ++ti) {
            const int c0 = wave * 256 + ti * 16;
            const ushort* kr = kbse + (size_t)(c0 + l15) * HDIM;
            const short8 k0 = *(const short8*)(kr + quad * 8);
            const short8 k1 = *(const short8*)(kr + 32 + quad * 8);
            f32x4 a = (f32x4){0.f, 0.f, 0.f, 0.f};
            a = __builtin_amdgcn_mfma_f32_16x16x32_bf16(qf0, k0, a, 0, 0, 0);
            a = __builtin_amdgcn_mfma_f32_16x16x32_bf16(qf1, k1, a, 0, 0, 0);
#pragma unroll
            for (int r = 0; r < 4; ++r) {
                // exp(s - 8) = exp2(s*log2e - 8*log2e)
                const float e = exp2f(fmaf(a[r], 1.44269504f, -11.54156035f));
                s4[r] += e;
                pLds[(rbase + r) * PLD + c0 + l15] = f2b(e);
            }
        }
        // wave-level row-sum over its 256 cols
#pragma unroll
        for (int off = 1; off < 16; off <<= 1)
#pragma unroll
            for (int r = 0; r < 4; ++r) s4[r] += __shfl_xor(s4[r], off, 16);
        if (l15 == 0)
#pragma unroll
            for (int r = 0; r < 4; ++r) redS[wave * 16 + rbase + r] = s4[r];
        __syncthreads();                                        // B1

        float rinv[4];
#pragma unroll
        for (int r = 0; r < 4; ++r) {
            float s = redS[rbase + r];
#pragma unroll
            for (int w = 1; w < 8; ++w) s += redS[w * 16 + rbase + r];
            rinv[r] = 1.0f / s;
        }
        // store rinv once per block (wave 0, l15==0 -> quads cover 16 rows)
        if (wave == 0 && l15 == 0) {
#pragma unroll
            for (int r = 0; r < 4; ++r)
                rinv_ws[(size_t)bh * S_LEN + sq0 + rbase + r] = rinv[r];
        }

        // ---- PV on unnormalized e; scale by rinv at the end ----
        const ushort* vrow = vt + ((size_t)bh * HDIM + ntile * 16 + l15) * S_LEN + khalf * 1024;
        const ushort* prow = &pLds[l15 * PLD + khalf * 1024];
        f32x4 o0 = (f32x4){0.f, 0.f, 0.f, 0.f}, o1 = o0;
#pragma unroll
        for (int st = 0; st < 32; st += 2) {
            const short8 pa0 = *(const short8*)(prow + st * 32 + quad * 8);
            const short8 vb0 = *(const short8*)(vrow + st * 32 + quad * 8);
            o0 = __builtin_amdgcn_mfma_f32_16x16x32_bf16(pa0, vb0, o0, 0, 0, 0);
            const short8 pa1 = *(const short8*)(prow + (st + 1) * 32 + quad * 8);
            const short8 vb1 = *(const short8*)(vrow + (st + 1) * 32 + quad * 8);
            o1 = __builtin_amdgcn_mfma_f32_16x16x32_bf16(pa1, vb1, o1, 0, 0, 0);
        }
        const f32x4 o = o0 + o1;
        if (khalf == 1) {
#pragma unroll
            for (int r = 0; r < 4; ++r)
                red2[ntile * 256 + (rbase + r) * 16 + l15] = o[r];
        }
        __syncthreads();                                        // B2
        if (khalf == 0) {
#pragma unroll
            for (int r = 0; r < 4; ++r) {
                const float val = (o[r] + red2[ntile * 256 + (rbase + r) * 16 + l15]) * rinv[r];
                const int s = sq0 + rbase + r;
                const int d = ntile * 16 + l15;
                ao[((size_t)s * BATCH + b) * EMB + h * HDIM + d] = f2b(val);
            }
        }
    }
}

// ---------------------------------------------------------------------------
// attn_avg recompute: out[b][sq][sk] = (1/16) sum_h exp2(S_h*log2e - c)*rinv.
// Same bf16 MFMA on same inputs -> bit-identical scores to attn_bf16; rinv
// stored fp32 -> e*rinv accumulated in FP32 (more accurate than old fp16
// partial path). Block = (b, 64 q-rows, 256 k-cols) x 16 heads, 512 blocks.
// XCD-chunked: logical>>6 = k-chunk -> each XCD's K working set = 1 MB (L2).
// Replaces pavg accumulation in attn + pavg_ws round-trip + avg_reduce.
// ---------------------------------------------------------------------------
__global__ __launch_bounds__(512, 2)
void pavg_scores(const ushort* __restrict__ qw, const ushort* __restrict__ kw,
                 const float* __restrict__ rinv_ws, float* __restrict__ out)
{
    const int t     = threadIdx.x;
    const int lane  = t & 63;
    const int wave  = t >> 6;              // 0..7
    const int quad  = lane >> 4;
    const int l15   = lane & 15;
    const int rbase = quad * 4;

    const int bid     = blockIdx.x;        // 0..511
    const int logical = (bid & 7) * 64 + (bid >> 3);
    const int kc      = logical >> 6;      // 0..7  k-chunk (256 cols)
    const int b       = (logical >> 5) & 1;
    const int sqc     = logical & 31;      // 0..31 sq-chunk (64 rows)

    const int k0row = kc * 256 + wave * 32;   // wave owns 2 k-tiles (32 rows)

    float pacc[4][2][4];
#pragma unroll
    for (int s4i = 0; s4i < 4; ++s4i)
#pragma unroll
        for (int t2 = 0; t2 < 2; ++t2)
#pragma unroll
            for (int r = 0; r < 4; ++r) pacc[s4i][t2][r] = 0.f;

    for (int h = 0; h < NHEAD; ++h) {
        const int bh = b * NHEAD + h;
        const ushort* kr0 = kw + ((size_t)bh * S_LEN + k0row + l15) * HDIM;
        const ushort* kr1 = kw + ((size_t)bh * S_LEN + k0row + 16 + l15) * HDIM;
        const short8 kf00 = *(const short8*)(kr0 + quad * 8);
        const short8 kf01 = *(const short8*)(kr0 + 32 + quad * 8);
        const short8 kf10 = *(const short8*)(kr1 + quad * 8);
        const short8 kf11 = *(const short8*)(kr1 + 32 + quad * 8);
        const float* rbse = rinv_ws + (size_t)bh * S_LEN + sqc * 64;
#pragma unroll
        for (int s4i = 0; s4i < 4; ++s4i) {
            const ushort* qbase = qw + ((size_t)bh * S_LEN + sqc * 64 + s4i * 16) * HDIM;
            const short8 qf0 = *(const short8*)(qbase + l15 * HDIM + quad * 8);
            const short8 qf1 = *(const short8*)(qbase + l15 * HDIM + 32 + quad * 8);
            f32x4 a0 = (f32x4){0.f, 0.f, 0.f, 0.f}, a1 = a0;
            a0 = __builtin_amdgcn_mfma_f32_16x16x32_bf16(qf0, kf00, a0, 0, 0, 0);
            a0 = __builtin_amdgcn_mfma_f32_16x16x32_bf16(qf1, kf01, a0, 0, 0, 0);
            a1 = __builtin_amdgcn_mfma_f32_16x16x32_bf16(qf0, kf10, a1, 0, 0, 0);
            a1 = __builtin_amdgcn_mfma_f32_16x16x32_bf16(qf1, kf11, a1, 0, 0, 0);
#pragma unroll
            for (int r = 0; r < 4; ++r) {
                const float ri = rbse[s4i * 16 + rbase + r];
                pacc[s4i][0][r] = fmaf(exp2f(fmaf(a0[r], 1.44269504f, -11.54156035f)), ri, pacc[s4i][0][r]);
                pacc[s4i][1][r] = fmaf(exp2f(fmaf(a1[r], 1.44269504f, -11.54156035f)), ri, pacc[s4i][1][r]);
            }
        }
    }

    const float inv16 = 0.0625f;
#pragma unroll
    for (int s4i = 0; s4i < 4; ++s4i)
#pragma unroll
        for (int t2 = 0; t2 < 2; ++t2)
#pragma unroll
            for (int r = 0; r < 4; ++r) {
                const int sq = sqc * 64 + s4i * 16 + rbase + r;
                const int sk = k0row + t2 * 16 + l15;
                out[((size_t)b * S_LEN + sq) * S_LEN + sk] = pacc[s4i][t2][r] * inv16;
            }
}

// ---------------------------------------------------------------------------
extern "C" void kernel_launch(void* const* d_in, const int* in_sizes, int n_in,
                              void* d_out, int out_size, void* d_ws, size_t ws_size,
                              hipStream_t stream)
{
    const float* query = (const float*)d_in[0];
    const float* key   = (const float*)d_in[1];
    const float* value = (const float*)d_in[2];
    const float* q_w   = (const float*)d_in[3];
    const float* q_b   = (const float*)d_in[4];
    const float* k_w   = (const float*)d_in[5];
    const float* k_b   = (const float*)d_in[6];
    const float* v_w   = (const float*)d_in[7];
    const float* v_b   = (const float*)d_in[8];
    const float* out_w = (const float*)d_in[9];
    const float* out_b = (const float*)d_in[10];

    float* Z        = (float*)d_out;                       // [S,B,E] fp32
    float* attn_avg = Z + (size_t)S_LEN * BATCH * EMB;     // [B,S,S] fp32

    const size_t QKV = (size_t)S_LEN * BATCH * EMB;        // 4,194,304
    ushort* q_ws    = (ushort*)d_ws;                       // bf16 [B*H][S][D]
    ushort* k_ws    = q_ws + QKV;                          // bf16 [B*H][S][D]
    ushort* vt_ws   = k_ws + QKV;                          // bf16 [B*H][D][S]
    ushort* ao_ws   = vt_ws + QKV;                         // bf16 [S][B][E]
    float*  rinv_ws = (float*)(ao_ws + QKV);               // fp32 [B*H][S]
    ushort* qbf     = (ushort*)(rinv_ws + (size_t)BATCH * NHEAD * S_LEN);
    ushort* kbf     = qbf + QKV;
    ushort* vbf     = kbf + QKV;
    ushort* wqb     = vbf + QKV;                           // bf16 weights [E][E]
    ushort* wkb     = wqb + (size_t)EMB * EMB;
    ushort* wvb     = wkb + (size_t)EMB * EMB;
    ushort* wob     = wvb + (size_t)EMB * EMB;

    // precast fp32 -> bf16 (inputs: 4M elems each; weights: 1M elems each)
    cast3<<<dim3(2048, 3), 256, 0, stream>>>(query, key, value, qbf, kbf, vbf);
    cast4<<<dim3(512, 4), 256, 0, stream>>>(q_w, k_w, v_w, out_w, wqb, wkb, wvb, wob);

    const dim3 blkG(512);
    const dim3 gq(32, 8, 3);                               // M/128 x N/128 x {q,k,v}
    gemm_qkv<<<gq, blkG, 0, stream>>>(qbf, kbf, vbf, wqb, wkb, wvb,
                                      q_b, k_b, v_b, q_ws, k_ws, vt_ws);

    attn_bf16<<<dim3(512), dim3(512), 0, stream>>>(q_ws, k_ws, vt_ws, ao_ws, rinv_ws);

    const dim3 gz(32, 8);
    gemm_z<<<gz, blkG, 0, stream>>>(ao_ws, wob, out_b, Z);

    pavg_scores<<<dim3(512), dim3(512), 0, stream>>>(q_ws, k_ws, rinv_ws, attn_avg);
}

// Round 10
// 491.962 us; speedup vs baseline: 1.0532x; 1.0532x over previous
//
#include <hip/hip_runtime.h>
#include <hip/hip_fp16.h>
#include <cstdint>
#include <cstddef>

#define S_LEN 2048
#define BATCH 2
#define EMB   1024
#define NHEAD 16
#define HDIM  64

typedef short short8 __attribute__((ext_vector_type(8)));   // 8 bf16 (4 VGPRs)
typedef float f32x4  __attribute__((ext_vector_type(4)));

__device__ __forceinline__ unsigned short f2b(float f) {
    unsigned int u = __float_as_uint(f);
    u = (u + 0x7FFFu + ((u >> 16) & 1u)) >> 16;   // RNE
    return (unsigned short)u;
}
__device__ __forceinline__ unsigned int pk2(float a, float b) {
    return (unsigned int)f2b(a) | ((unsigned int)f2b(b) << 16);
}
__device__ __forceinline__ float b2f_lo(unsigned int u) { return __uint_as_float(u << 16); }
__device__ __forceinline__ float b2f_hi(unsigned int u) { return __uint_as_float(u & 0xFFFF0000u); }

// async global->LDS, 16B per lane. LDS dest is wave-uniform base + lane*16.
__device__ __forceinline__ void gload_lds16(const ushort* g, ushort* l) {
    __builtin_amdgcn_global_load_lds(
        (const __attribute__((address_space(1))) void*)g,
        (__attribute__((address_space(3))) void*)l, 16, 0, 0);
}

// ---------------------------------------------------------------------------
// Precast fp32 -> bf16 (RNE, identical to the f2b the GEMM used in-kernel).
// ---------------------------------------------------------------------------
__global__ __launch_bounds__(256)
void cast3(const float* __restrict__ s0, const float* __restrict__ s1,
           const float* __restrict__ s2, ushort* __restrict__ d0,
           ushort* __restrict__ d1, ushort* __restrict__ d2)
{
    const float* s = (blockIdx.y == 0) ? s0 : (blockIdx.y == 1) ? s1 : s2;
    ushort*      d = (blockIdx.y == 0) ? d0 : (blockIdx.y == 1) ? d1 : d2;
    const size_t i = ((size_t)blockIdx.x * 256 + threadIdx.x) * 8;
    const float4 a = *(const float4*)(s + i);
    const float4 b = *(const float4*)(s + i + 4);
    *(uint4*)(d + i) = make_uint4(pk2(a.x, a.y), pk2(a.z, a.w),
                                  pk2(b.x, b.y), pk2(b.z, b.w));
}

__global__ __launch_bounds__(256)
void cast4(const float* __restrict__ s0, const float* __restrict__ s1,
           const float* __restrict__ s2, const float* __restrict__ s3,
           ushort* __restrict__ d0, ushort* __restrict__ d1,
           ushort* __restrict__ d2, ushort* __restrict__ d3)
{
    const float* s = (blockIdx.y == 0) ? s0 : (blockIdx.y == 1) ? s1
                   : (blockIdx.y == 2) ? s2 : s3;
    ushort*      d = (blockIdx.y == 0) ? d0 : (blockIdx.y == 1) ? d1
                   : (blockIdx.y == 2) ? d2 : d3;
    const size_t i = ((size_t)blockIdx.x * 256 + threadIdx.x) * 8;
    const float4 a = *(const float4*)(s + i);
    const float4 b = *(const float4*)(s + i + 4);
    *(uint4*)(d + i) = make_uint4(pk2(a.x, a.y), pk2(a.z, a.w),
                                  pk2(b.x, b.y), pk2(b.z, b.w));
}

// ---------------------------------------------------------------------------
// bf16 GEMM: C[M=4096,N=1024] = A[M,K=1024] @ W[N,K]^T + bias.
// 128x128 tile, BK=32, 512 thr / 8 waves, global_load_lds width-16 staging,
// double-buffered LDS, XOR seg-swizzle (src-side + read-side). Unchanged R2.
// ---------------------------------------------------------------------------
__device__ __forceinline__ void gemm_core(
    ushort (*As)[128 * 32], ushort (*Bs)[128 * 32],
    const ushort* __restrict__ A, const ushort* __restrict__ W,
    const float* __restrict__ bias, void* __restrict__ out_,
    float scale, int mode)
{
    constexpr int K  = EMB;
    constexpr int NT = K / 32;           // 32 K-steps

    const int t    = threadIdx.x;
    const int lane = t & 63;
    const int wave = t >> 6;
    const int quad = lane >> 4;
    const int l15  = lane & 15;
    const int wm   = wave >> 2;          // 0..1
    const int wn   = wave & 3;           // 0..3
    const int m0   = blockIdx.x * 128;
    const int n0   = blockIdx.y * 128;

    const int srow = t >> 2;
    const int sseg = ((t & 3) ^ ((srow >> 1) & 3)) << 3;   // elems
    const ushort* gA = A + (size_t)(m0 + srow) * K + sseg;
    const ushort* gW = W + (size_t)(n0 + srow) * K + sseg;

    f32x4 acc[4][2];
#pragma unroll
    for (int mi = 0; mi < 4; ++mi)
#pragma unroll
        for (int ni = 0; ni < 2; ++ni) acc[mi][ni] = (f32x4){0.f, 0.f, 0.f, 0.f};

#define STAGE(buf, kt) do {                         \
        gload_lds16(gA + (kt) * 32, &As[buf][t * 8]); \
        gload_lds16(gW + (kt) * 32, &Bs[buf][t * 8]); \
    } while (0)

    STAGE(0, 0);
    __syncthreads();

    for (int kt = 0; kt < NT; ++kt) {
        const int cur = kt & 1;
        if (kt + 1 < NT) STAGE(cur ^ 1, kt + 1);
        short8 af[4], bf[2];
#pragma unroll
        for (int mi = 0; mi < 4; ++mi) {
            const int ra = wm * 64 + mi * 16 + l15;
            af[mi] = *(const short8*)&As[cur][ra * 32 + ((quad ^ ((ra >> 1) & 3)) << 3)];
        }
#pragma unroll
        for (int ni = 0; ni < 2; ++ni) {
            const int rb = wn * 32 + ni * 16 + l15;
            bf[ni] = *(const short8*)&Bs[cur][rb * 32 + ((quad ^ ((rb >> 1) & 3)) << 3)];
        }
#pragma unroll
        for (int mi = 0; mi < 4; ++mi)
#pragma unroll
            for (int ni = 0; ni < 2; ++ni)
                acc[mi][ni] = __builtin_amdgcn_mfma_f32_16x16x32_bf16(
                    af[mi], bf[ni], acc[mi][ni], 0, 0, 0);
        __syncthreads();
    }
#undef STAGE

#pragma unroll
    for (int mi = 0; mi < 4; ++mi)
#pragma unroll
        for (int ni = 0; ni < 2; ++ni) {
            const int col = n0 + wn * 32 + ni * 16 + l15;
            const float bc = bias[col];
#pragma unroll
            for (int r = 0; r < 4; ++r) {
                const int rg = m0 + wm * 64 + mi * 16 + quad * 4 + r;
                const float v = (acc[mi][ni][r] + bc) * scale;
                if (mode == 0) {
                    ((float*)out_)[(size_t)rg * EMB + col] = v;
                } else {
                    const int s  = rg >> 1;
                    const int bb = rg & 1;
                    const int h  = col >> 6;
                    const int d  = col & 63;
                    if (mode == 1)
                        ((ushort*)out_)[(((size_t)(bb * NHEAD + h)) * S_LEN + s) * HDIM + d] = f2b(v);
                    else
                        ((ushort*)out_)[(((size_t)(bb * NHEAD + h)) * HDIM + d) * S_LEN + s] = f2b(v);
                }
            }
        }
}

__global__ __launch_bounds__(512, 2)
void gemm_qkv(const ushort* __restrict__ qi, const ushort* __restrict__ ki,
              const ushort* __restrict__ vi,
              const ushort* __restrict__ qW, const ushort* __restrict__ kW,
              const ushort* __restrict__ vW,
              const float* __restrict__ qB, const float* __restrict__ kB,
              const float* __restrict__ vB,
              ushort* __restrict__ qO, ushort* __restrict__ kO,
              ushort* __restrict__ vO)
{
    __shared__ ushort As[2][128 * 32];
    __shared__ ushort Bs[2][128 * 32];
    const int z = blockIdx.z;
    const ushort* A    = (z == 0) ? qi : (z == 1) ? ki : vi;
    const ushort* W    = (z == 0) ? qW : (z == 1) ? kW : vW;
    const float* bias  = (z == 0) ? qB : (z == 1) ? kB : vB;
    ushort* out        = (z == 0) ? qO : (z == 1) ? kO : vO;
    const float scale  = (z == 0) ? 0.125f : 1.0f;
    const int   mode   = (z == 2) ? 2 : 1;
    gemm_core(As, Bs, A, W, bias, out, scale, mode);
}

__global__ __launch_bounds__(512, 2)
void gemm_z(const ushort* __restrict__ A, const ushort* __restrict__ W,
            const float* __restrict__ bias, float* __restrict__ out)
{
    __shared__ ushort As[2][128 * 32];
    __shared__ ushort Bs[2][128 * 32];
    gemm_core(As, Bs, A, W, bias, out, 1.0f, 0);
}

// ---------------------------------------------------------------------------
// Fused attention — UNCHANGED from R9 (proven: 60 VGPR, no spill, ~40% occ,
// 257 us). pavg lives in pavg_scores; rinv stored for it.
// ---------------------------------------------------------------------------
#define PLD 2056   // 2048 + 8 pad (ushorts)
__global__ __launch_bounds__(512, 4)
void attn_bf16(const ushort* __restrict__ qw, const ushort* __restrict__ kw,
               const ushort* __restrict__ vt, ushort* __restrict__ ao,
               float* __restrict__ rinv_ws)
{
    __shared__ ushort pLds[16 * PLD];      // 65792 B (unnormalized e, bf16)
    __shared__ float  redS[8 * 16];        // per-wave row-sum partials
    __shared__ float  red2[4 * 16 * 16];   // PV khalf partials

    const int t     = threadIdx.x;
    const int lane  = t & 63;
    const int wave  = t >> 6;              // 0..7
    const int quad  = lane >> 4;
    const int l15   = lane & 15;
    const int rbase = quad * 4;

    const int bid     = blockIdx.x;
    const int logical = (bid & 7) * 64 + (bid >> 3);
    const int qt      = logical & 127;     // q-tile 0..127
    const int rest    = logical >> 7;      // 0..3
    const int b       = rest & 1;
    const int g       = rest >> 1;         // head group
    const int sq0     = qt * 16;

    const int ntile = wave & 3;            // PV d-tile
    const int khalf = wave >> 2;           // PV k-half

    for (int hh = 0; hh < 8; ++hh) {
        const int h  = g * 8 + hh;
        const int bh = b * NHEAD + h;
        const ushort* qbase = qw + ((size_t)bh * S_LEN + sq0) * HDIM;
        const ushort* kbse  = kw + (size_t)bh * S_LEN * HDIM;

        const short8 qf0 = *(const short8*)(qbase + l15 * HDIM + quad * 8);
        const short8 qf1 = *(const short8*)(qbase + l15 * HDIM + 32 + quad * 8);

        // ---- scores + exp + stage (wave owns cols [wave*256, wave*256+256)) ----
        float s4[4] = {0.f, 0.f, 0.f, 0.f};
#pragma unroll
        for (int ti = 0; ti < 16; ++ti) {
            const int c0 = wave * 256 + ti * 16;
            const ushort* kr = kbse + (size_t)(c0 + l15) * HDIM;
            const short8 k0 = *(const short8*)(kr + quad * 8);
            const short8 k1 = *(const short8*)(kr + 32 + quad * 8);
            f32x4 a = (f32x4){0.f, 0.f, 0.f, 0.f};
            a = __builtin_amdgcn_mfma_f32_16x16x32_bf16(qf0, k0, a, 0, 0, 0);
            a = __builtin_amdgcn_mfma_f32_16x16x32_bf16(qf1, k1, a, 0, 0, 0);
#pragma unroll
            for (int r = 0; r < 4; ++r) {
                // exp(s - 8) = exp2(s*log2e - 8*log2e)
                const float e = exp2f(fmaf(a[r], 1.44269504f, -11.54156035f));
                s4[r] += e;
                pLds[(rbase + r) * PLD + c0 + l15] = f2b(e);
            }
        }
        // wave-level row-sum over its 256 cols
#pragma unroll
        for (int off = 1; off < 16; off <<= 1)
#pragma unroll
            for (int r = 0; r < 4; ++r) s4[r] += __shfl_xor(s4[r], off, 16);
        if (l15 == 0)
#pragma unroll
            for (int r = 0; r < 4; ++r) redS[wave * 16 + rbase + r] = s4[r];
        __syncthreads();                                        // B1

        float rinv[4];
#pragma unroll
        for (int r = 0; r < 4; ++r) {
            float s = redS[rbase + r];
#pragma unroll
            for (int w = 1; w < 8; ++w) s += redS[w * 16 + rbase + r];
            rinv[r] = 1.0f / s;
        }
        // store rinv once per block (wave 0, l15==0 -> quads cover 16 rows)
        if (wave == 0 && l15 == 0) {
#pragma unroll
            for (int r = 0; r < 4; ++r)
                rinv_ws[(size_t)bh * S_LEN + sq0 + rbase + r] = rinv[r];
        }

        // ---- PV on unnormalized e; scale by rinv at the end ----
        const ushort* vrow = vt + ((size_t)bh * HDIM + ntile * 16 + l15) * S_LEN + khalf * 1024;
        const ushort* prow = &pLds[l15 * PLD + khalf * 1024];
        f32x4 o0 = (f32x4){0.f, 0.f, 0.f, 0.f}, o1 = o0;
#pragma unroll
        for (int st = 0; st < 32; st += 2) {
            const short8 pa0 = *(const short8*)(prow + st * 32 + quad * 8);
            const short8 vb0 = *(const short8*)(vrow + st * 32 + quad * 8);
            o0 = __builtin_amdgcn_mfma_f32_16x16x32_bf16(pa0, vb0, o0, 0, 0, 0);
            const short8 pa1 = *(const short8*)(prow + (st + 1) * 32 + quad * 8);
            const short8 vb1 = *(const short8*)(vrow + (st + 1) * 32 + quad * 8);
            o1 = __builtin_amdgcn_mfma_f32_16x16x32_bf16(pa1, vb1, o1, 0, 0, 0);
        }
        const f32x4 o = o0 + o1;
        if (khalf == 1) {
#pragma unroll
            for (int r = 0; r < 4; ++r)
                red2[ntile * 256 + (rbase + r) * 16 + l15] = o[r];
        }
        __syncthreads();                                        // B2
        if (khalf == 0) {
#pragma unroll
            for (int r = 0; r < 4; ++r) {
                const float val = (o[r] + red2[ntile * 256 + (rbase + r) * 16 + l15]) * rinv[r];
                const int s = sq0 + rbase + r;
                const int d = ntile * 16 + l15;
                ao[((size_t)s * BATCH + b) * EMB + h * HDIM + d] = f2b(val);
            }
        }
    }
}

// ---------------------------------------------------------------------------
// attn_avg recompute v2 — R10: R9's version was ~105 us (vs ~15 us of real
// work): the 16-head loop stalled on 4 dependent K-fragment global loads per
// head + per-element scalar rinv global loads; no cross-head pipelining.
// Fix = gemm_core treatment: (1) K-tile (256x64 bf16, 32 KB) double-buffered
// in LDS via global_load_lds w16, head h+1 staged BEFORE computing head h,
// 1 barrier/head; (2) rule-21 both-sides XOR seg-swizzle (linear LDS dest,
// inverse-swizzled global src, swizzled ds_read) -> kfrag ds_read_b128 ~2-way
// conflict (free); (3) all 16 heads' rinv pre-staged to LDS (4 KB) once.
// LDS 68 KB -> 2 blocks/CU. Math bit-identical to v1 -> absmax unchanged.
// ---------------------------------------------------------------------------
__global__ __launch_bounds__(512, 2)
void pavg_scores(const ushort* __restrict__ qw, const ushort* __restrict__ kw,
                 const float* __restrict__ rinv_ws, float* __restrict__ out)
{
    __shared__ ushort Kb[2][256 * 64];     // 2 x 32 KB (XOR seg-swizzled)
    __shared__ float  rl[16 * 64];         // rinv, all heads (4 KB)

    const int t     = threadIdx.x;
    const int lane  = t & 63;
    const int wave  = t >> 6;              // 0..7
    const int quad  = lane >> 4;
    const int l15   = lane & 15;
    const int rbase = quad * 4;

    const int bid     = blockIdx.x;        // 0..511
    const int logical = (bid & 7) * 64 + (bid >> 3);
    const int kc      = logical >> 6;      // 0..7  k-chunk (256 cols)
    const int b       = (logical >> 5) & 1;
    const int sqc     = logical & 31;      // 0..31 sq-chunk (64 rows)
    const int k0row   = kc * 256;

    // stage rinv for all 16 heads: rl[h*64 + i]
    {
        int j = t;
        rl[j] = rinv_ws[((size_t)b * NHEAD + (j >> 6)) * S_LEN + sqc * 64 + (j & 63)];
        j = t + 512;
        rl[j] = rinv_ws[((size_t)b * NHEAD + (j >> 6)) * S_LEN + sqc * 64 + (j & 63)];
    }

    // K stage: 32 KB = 4 x (512 thr x 16B). Linear LDS dest (idx*16B);
    // global source pre-swizzled: phys seg p at row r holds logical seg p^(r&7).
#define STAGEK(buf, h) do {                                                    \
        const ushort* kg = kw + ((size_t)(b * NHEAD + (h)) * S_LEN + k0row) * HDIM; \
        _Pragma("unroll")                                                      \
        for (int i = 0; i < 4; ++i) {                                          \
            const int idx = i * 512 + t;                                       \
            const int rr  = idx >> 3;                                          \
            const int ss  = (idx & 7) ^ (rr & 7);                              \
            gload_lds16(kg + rr * HDIM + ss * 8, &Kb[buf][idx * 8]);           \
        }                                                                      \
    } while (0)

    float pacc[4][2][4];
#pragma unroll
    for (int s4i = 0; s4i < 4; ++s4i)
#pragma unroll
        for (int t2 = 0; t2 < 2; ++t2)
#pragma unroll
            for (int r = 0; r < 4; ++r) pacc[s4i][t2][r] = 0.f;

    STAGEK(0, 0);
    __syncthreads();

    for (int h = 0; h < NHEAD; ++h) {
        const int cur = h & 1;
        if (h + 1 < NHEAD) STAGEK(cur ^ 1, h + 1);

        // kfrags from LDS (swizzled read): rows wave*32+l15 and +16
        const int r0 = wave * 32 + l15;
        const int r1 = r0 + 16;
        const short8 kf00 = *(const short8*)&Kb[cur][r0 * 64 + ((quad       ^ (r0 & 7)) << 3)];
        const short8 kf01 = *(const short8*)&Kb[cur][r0 * 64 + (((quad + 4) ^ (r0 & 7)) << 3)];
        const short8 kf10 = *(const short8*)&Kb[cur][r1 * 64 + ((quad       ^ (r1 & 7)) << 3)];
        const short8 kf11 = *(const short8*)&Kb[cur][r1 * 64 + (((quad + 4) ^ (r1 & 7)) << 3)];

        const int bh = b * NHEAD + h;
#pragma unroll
        for (int s4i = 0; s4i < 4; ++s4i) {
            const ushort* qbase = qw + ((size_t)bh * S_LEN + sqc * 64 + s4i * 16) * HDIM;
            const short8 qf0 = *(const short8*)(qbase + l15 * HDIM + quad * 8);
            const short8 qf1 = *(const short8*)(qbase + l15 * HDIM + 32 + quad * 8);
            f32x4 a0 = (f32x4){0.f, 0.f, 0.f, 0.f}, a1 = a0;
            a0 = __builtin_amdgcn_mfma_f32_16x16x32_bf16(qf0, kf00, a0, 0, 0, 0);
            a0 = __builtin_amdgcn_mfma_f32_16x16x32_bf16(qf1, kf01, a0, 0, 0, 0);
            a1 = __builtin_amdgcn_mfma_f32_16x16x32_bf16(qf0, kf10, a1, 0, 0, 0);
            a1 = __builtin_amdgcn_mfma_f32_16x16x32_bf16(qf1, kf11, a1, 0, 0, 0);
#pragma unroll
            for (int r = 0; r < 4; ++r) {
                const float ri = rl[h * 64 + s4i * 16 + rbase + r];
                pacc[s4i][0][r] = fmaf(exp2f(fmaf(a0[r], 1.44269504f, -11.54156035f)), ri, pacc[s4i][0][r]);
                pacc[s4i][1][r] = fmaf(exp2f(fmaf(a1[r], 1.44269504f, -11.54156035f)), ri, pacc[s4i][1][r]);
            }
        }
        __syncthreads();   // drains stage (vmcnt) + kfrag reads before overwrite
    }
#undef STAGEK

    const float inv16 = 0.0625f;
#pragma unroll
    for (int s4i = 0; s4i < 4; ++s4i)
#pragma unroll
        for (int t2 = 0; t2 < 2; ++t2)
#pragma unroll
            for (int r = 0; r < 4; ++r) {
                const int sq = sqc * 64 + s4i * 16 + rbase + r;
                const int sk = k0row + wave * 32 + t2 * 16 + l15;
                out[((size_t)b * S_LEN + sq) * S_LEN + sk] = pacc[s4i][t2][r] * inv16;
            }
}

// ---------------------------------------------------------------------------
extern "C" void kernel_launch(void* const* d_in, const int* in_sizes, int n_in,
                              void* d_out, int out_size, void* d_ws, size_t ws_size,
                              hipStream_t stream)
{
    const float* query = (const float*)d_in[0];
    const float* key   = (const float*)d_in[1];
    const float* value = (const float*)d_in[2];
    const float* q_w   = (const float*)d_in[3];
    const float* q_b   = (const float*)d_in[4];
    const float* k_w   = (const float*)d_in[5];
    const float* k_b   = (const float*)d_in[6];
    const float* v_w   = (const float*)d_in[7];
    const float* v_b   = (const float*)d_in[8];
    const float* out_w = (const float*)d_in[9];
    const float* out_b = (const float*)d_in[10];

    float* Z        = (float*)d_out;                       // [S,B,E] fp32
    float* attn_avg = Z + (size_t)S_LEN * BATCH * EMB;     // [B,S,S] fp32

    const size_t QKV = (size_t)S_LEN * BATCH * EMB;        // 4,194,304
    ushort* q_ws    = (ushort*)d_ws;                       // bf16 [B*H][S][D]
    ushort* k_ws    = q_ws + QKV;                          // bf16 [B*H][S][D]
    ushort* vt_ws   = k_ws + QKV;                          // bf16 [B*H][D][S]
    ushort* ao_ws   = vt_ws + QKV;                         // bf16 [S][B][E]
    float*  rinv_ws = (float*)(ao_ws + QKV);               // fp32 [B*H][S]
    ushort* qbf     = (ushort*)(rinv_ws + (size_t)BATCH * NHEAD * S_LEN);
    ushort* kbf     = qbf + QKV;
    ushort* vbf     = kbf + QKV;
    ushort* wqb     = vbf + QKV;                           // bf16 weights [E][E]
    ushort* wkb     = wqb + (size_t)EMB * EMB;
    ushort* wvb     = wkb + (size_t)EMB * EMB;
    ushort* wob     = wvb + (size_t)EMB * EMB;

    // precast fp32 -> bf16 (inputs: 4M elems each; weights: 1M elems each)
    cast3<<<dim3(2048, 3), 256, 0, stream>>>(query, key, value, qbf, kbf, vbf);
    cast4<<<dim3(512, 4), 256, 0, stream>>>(q_w, k_w, v_w, out_w, wqb, wkb, wvb, wob);

    const dim3 blkG(512);
    const dim3 gq(32, 8, 3);                               // M/128 x N/128 x {q,k,v}
    gemm_qkv<<<gq, blkG, 0, stream>>>(qbf, kbf, vbf, wqb, wkb, wvb,
                                      q_b, k_b, v_b, q_ws, k_ws, vt_ws);

    attn_bf16<<<dim3(512), dim3(512), 0, stream>>>(q_ws, k_ws, vt_ws, ao_ws, rinv_ws);

    const dim3 gz(32, 8);
    gemm_z<<<gz, blkG, 0, stream>>>(ao_ws, wob, out_b, Z);

    pavg_scores<<<dim3(512), dim3(512), 0, stream>>>(q_ws, k_ws, rinv_ws, attn_avg);
}